// Round 5
// baseline (866.502 us; speedup 1.0000x reference)
//
#include <hip/hip_runtime.h>
#include <cstdint>

// ---------------------------------------------------------------------------
// LaSSMDecoder on MI355X — fp32 baseline, chunked (SSD) Mamba2 scan.
// Round 5: KNN wave-shared threshold tau = wave_min(bd7) gates the insert
// chain (round 4 paid the 39-instr chain ~every iter because ANY of 64 lanes
// inserting makes the wave execute it; tau filter drops that to ~25%).
// ---------------------------------------------------------------------------

__device__ __forceinline__ bool knn_less(float d, int i, float dref, int iref) {
  return d < dref || (d == dref && i < iref);
}

// Guarded branchless one-slot insert (safe for non-qualifying candidates:
// if d >= bd7 nothing changes). All state in named registers.
#define KNN_INS_G(dv, iv)                                                      \
  do {                                                                         \
    const float _d = (dv); const int _i = (iv);                                \
    const bool a0 = _d < bd0;                                                  \
    const bool a1 = _d < bd1;                                                  \
    const bool a2 = _d < bd2;                                                  \
    const bool a3 = _d < bd3;                                                  \
    const bool a4 = _d < bd4;                                                  \
    const bool a5 = _d < bd5;                                                  \
    const bool a6 = _d < bd6;                                                  \
    const bool a7 = _d < bd7;                                                  \
    bd7 = a6 ? bd6 : (a7 ? _d : bd7); bi7 = a6 ? bi6 : (a7 ? _i : bi7);        \
    bd6 = a5 ? bd5 : (a6 ? _d : bd6); bi6 = a5 ? bi5 : (a6 ? _i : bi6);        \
    bd5 = a4 ? bd4 : (a5 ? _d : bd5); bi5 = a4 ? bi4 : (a5 ? _i : bi5);        \
    bd4 = a3 ? bd3 : (a4 ? _d : bd4); bi4 = a3 ? bi3 : (a4 ? _i : bi4);        \
    bd3 = a2 ? bd2 : (a3 ? _d : bd3); bi3 = a2 ? bi2 : (a3 ? _i : bi3);        \
    bd2 = a1 ? bd1 : (a2 ? _d : bd2); bi2 = a1 ? bi1 : (a2 ? _i : bi2);        \
    bd1 = a0 ? bd0 : (a1 ? _d : bd1); bi1 = a0 ? bi0 : (a1 ? _i : bi1);        \
    bd0 = a0 ? _d : bd0;              bi0 = a0 ? _i : bi0;                     \
  } while (0)

// Lexicographic insert for merge phases; caller pre-qualifies vs slot 7.
#define KNN_INS_LEX(dv, iv)                                                    \
  do {                                                                         \
    const float _d = (dv); const int _i = (iv);                                \
    const bool a0 = knn_less(_d, _i, bd0, bi0);                                \
    const bool a1 = knn_less(_d, _i, bd1, bi1);                                \
    const bool a2 = knn_less(_d, _i, bd2, bi2);                                \
    const bool a3 = knn_less(_d, _i, bd3, bi3);                                \
    const bool a4 = knn_less(_d, _i, bd4, bi4);                                \
    const bool a5 = knn_less(_d, _i, bd5, bi5);                                \
    const bool a6 = knn_less(_d, _i, bd6, bi6);                                \
    bd7 = a6 ? bd6 : _d;              bi7 = a6 ? bi6 : _i;                     \
    bd6 = a5 ? bd5 : (a6 ? _d : bd6); bi6 = a5 ? bi5 : (a6 ? _i : bi6);        \
    bd5 = a4 ? bd4 : (a5 ? _d : bd5); bi5 = a4 ? bi4 : (a5 ? _i : bi5);        \
    bd4 = a3 ? bd3 : (a4 ? _d : bd4); bi4 = a3 ? bi3 : (a4 ? _i : bi4);        \
    bd3 = a2 ? bd2 : (a3 ? _d : bd3); bi3 = a2 ? bi2 : (a3 ? _i : bi3);        \
    bd2 = a1 ? bd1 : (a2 ? _d : bd2); bi2 = a1 ? bi1 : (a2 ? _i : bi2);        \
    bd1 = a0 ? bd0 : (a1 ? _d : bd1); bi1 = a0 ? bi0 : (a1 ? _i : bi1);        \
    bd0 = a0 ? _d : bd0;              bi0 = a0 ? _i : bi0;                     \
  } while (0)

#define KNN_RESET()                                                            \
  do {                                                                         \
    bd0=bd1=bd2=bd3=bd4=bd5=bd6=bd7 = 3.4e38f;                                 \
    bi0=bi1=bi2=bi3=bi4=bi5=bi6=bi7 = 0x7fffffff;                              \
  } while (0)

// -------------------------- KNN (top-8 by squared distance) ----------------
__global__ __launch_bounds__(256) void knn_kernel(
    const float* __restrict__ qpos, const float* __restrict__ spos,
    int* __restrict__ idx_out)
{
#pragma clang fp contract(off)
  __shared__ float sd[2048];   // [8][256] transposed: sd[j*256+t]
  __shared__ int   si[2048];
  const int q = blockIdx.x, tid = threadIdx.x;
  const float qx = qpos[q*3+0], qy = qpos[q*3+1], qz = qpos[q*3+2];
  const float qq = qx*qx + qy*qy + qz*qz;
  float bd0,bd1,bd2,bd3,bd4,bd5,bd6,bd7;
  int   bi0,bi1,bi2,bi3,bi4,bi5,bi6,bi7;
  KNN_RESET();
  float tau = 3.4e38f;   // wave-min of lane bd7 (upper bound on global 8th)
  // phase 0: per-thread top-8; insert chain gated by wave-uniform tau test.
  for (int n = tid; n < 32768; n += 256) {
    const float sx = spos[n*3+0], sy = spos[n*3+1], sz = spos[n*3+2];
    const float ss = sx*sx + sy*sy + sz*sz;
    const float dot = qx*sx + qy*sy + qz*sz;
    const float d2 = (qq + ss) - 2.0f*dot;   // reference's exact formula
    // Safe skip: d2 >= tau >= global-8th-so-far >= final-8th; ties at tau
    // lose lexicographically (earlier arrival = smaller index holds the slot).
    if (__any(d2 < tau)) {
      KNN_INS_G(d2, n);
      float t = bd7;
#pragma unroll
      for (int off = 32; off; off >>= 1) t = fminf(t, __shfl_xor(t, off));
      tau = t;
    }
  }
  // stage to LDS, transposed (consecutive tid → consecutive banks)
  sd[0*256+tid]=bd0; sd[1*256+tid]=bd1; sd[2*256+tid]=bd2; sd[3*256+tid]=bd3;
  sd[4*256+tid]=bd4; sd[5*256+tid]=bd5; sd[6*256+tid]=bd6; sd[7*256+tid]=bd7;
  si[0*256+tid]=bi0; si[1*256+tid]=bi1; si[2*256+tid]=bi2; si[3*256+tid]=bi3;
  si[4*256+tid]=bi4; si[5*256+tid]=bi5; si[6*256+tid]=bi6; si[7*256+tid]=bi7;
  __syncthreads();
  // phase 1: 8 threads, each merges 32 source threads' sorted lists
  if (tid < 8) {
    KNN_RESET();
    for (int s = tid*32; s < tid*32 + 32; ++s) {
#pragma unroll
      for (int j = 0; j < 8; ++j) {
        const float d2 = sd[j*256 + s];
        const int   ii = si[j*256 + s];
        if (!knn_less(d2, ii, bd7, bi7)) break;  // source sorted → done
        KNN_INS_LEX(d2, ii);
      }
    }
  }
  __syncthreads();   // all phase-1 reads complete before overwrite
  if (tid < 8) {
    sd[0*256+tid]=bd0; sd[1*256+tid]=bd1; sd[2*256+tid]=bd2; sd[3*256+tid]=bd3;
    sd[4*256+tid]=bd4; sd[5*256+tid]=bd5; sd[6*256+tid]=bd6; sd[7*256+tid]=bd7;
    si[0*256+tid]=bi0; si[1*256+tid]=bi1; si[2*256+tid]=bi2; si[3*256+tid]=bi3;
    si[4*256+tid]=bi4; si[5*256+tid]=bi5; si[6*256+tid]=bi6; si[7*256+tid]=bi7;
  }
  __syncthreads();
  // phase 2: thread 0 merges the 8 surviving lists
  if (tid == 0) {
    KNN_RESET();
    for (int s = 0; s < 8; ++s) {
#pragma unroll
      for (int j = 0; j < 8; ++j) {
        const float d2 = sd[j*256 + s];
        const int   ii = si[j*256 + s];
        if (!knn_less(d2, ii, bd7, bi7)) break;
        KNN_INS_LEX(d2, ii);
      }
    }
    idx_out[q*8+0]=bi0; idx_out[q*8+1]=bi1; idx_out[q*8+2]=bi2; idx_out[q*8+3]=bi3;
    idx_out[q*8+4]=bi4; idx_out[q*8+5]=bi5; idx_out[q*8+6]=bi6; idx_out[q*8+7]=bi7;
  }
}

// -------------------------- inverse permutation ----------------------------
__global__ void inv_kernel(const int* __restrict__ order, int* __restrict__ inv)
{
  int i = blockIdx.x*blockDim.x + threadIdx.x;
  if (i < 4096) { int b = i >> 11, t = i & 2047; inv[(b<<11) + order[i]] = t; }
}

// -------------------------- generic tiled GEMM: Y = act(A[rowmap]@Wt^T + b) -
// A: [*, Kd] rows selected by rowmap (nullptr = identity); Wt: [Nn, Kd]
// act: 0 = none, 1 = exact gelu
__global__ __launch_bounds__(256) void gemm_kernel(
    const float* __restrict__ A, const int* __restrict__ rowmap,
    const float* __restrict__ Wt, const float* __restrict__ bias,
    float* __restrict__ Y, int M, int Nn, int Kd, int act)
{
  __shared__ float As[16][128];
  __shared__ float Ws[16][64];
  const int tid = threadIdx.x;
  const int bm = blockIdx.x, bn = blockIdx.y;
  const int tx = tid & 15, ty = tid >> 4;          // 16 x 16 thread grid
  const int ar = tid >> 1, ac = (tid & 1) << 3;    // A-tile load map (128x16)
  const int wr = tid >> 2, wc = (tid & 3) << 2;    // W-tile load map (64x16)
  int arow = bm*128 + ar;
  int asrc = rowmap ? rowmap[arow] : arow;
  const float* Arow = A + (size_t)asrc * Kd;
  int wrow = bn*64 + wr;
  const float* Wrow = (wrow < Nn) ? (Wt + (size_t)wrow * Kd) : nullptr;
  float acc[8][4];
#pragma unroll
  for (int i = 0; i < 8; ++i)
#pragma unroll
    for (int j = 0; j < 4; ++j) acc[i][j] = 0.f;
  for (int k0 = 0; k0 < Kd; k0 += 16) {
    float4 a0 = *(const float4*)(Arow + k0 + ac);
    float4 a1 = *(const float4*)(Arow + k0 + ac + 4);
    float4 w0 = Wrow ? *(const float4*)(Wrow + k0 + wc) : make_float4(0.f,0.f,0.f,0.f);
    As[ac+0][ar] = a0.x; As[ac+1][ar] = a0.y; As[ac+2][ar] = a0.z; As[ac+3][ar] = a0.w;
    As[ac+4][ar] = a1.x; As[ac+5][ar] = a1.y; As[ac+6][ar] = a1.z; As[ac+7][ar] = a1.w;
    Ws[wc+0][wr] = w0.x; Ws[wc+1][wr] = w0.y; Ws[wc+2][wr] = w0.z; Ws[wc+3][wr] = w0.w;
    __syncthreads();
#pragma unroll
    for (int k = 0; k < 16; ++k) {
      float4 aa0 = *(const float4*)&As[k][ty*8];
      float4 aa1 = *(const float4*)&As[k][ty*8+4];
      float4 bb  = *(const float4*)&Ws[k][tx*4];
      float am[8] = {aa0.x,aa0.y,aa0.z,aa0.w,aa1.x,aa1.y,aa1.z,aa1.w};
      float bv[4] = {bb.x,bb.y,bb.z,bb.w};
#pragma unroll
      for (int i = 0; i < 8; ++i)
#pragma unroll
        for (int j = 0; j < 4; ++j)
          acc[i][j] = fmaf(am[i], bv[j], acc[i][j]);
    }
    __syncthreads();
  }
#pragma unroll
  for (int i = 0; i < 8; ++i) {
    int m = bm*128 + ty*8 + i;   // all M here are multiples of 128
#pragma unroll
    for (int j = 0; j < 4; ++j) {
      int n = bn*64 + tx*4 + j;
      if (n < Nn) {
        float v = acc[i][j];
        if (bias) v += bias[n];
        if (act == 1) v = 0.5f*v*(1.f + erff(v*0.7071067811865475f));
        Y[(size_t)m*Nn + n] = v;
      }
    }
  }
}

// -------------------------- kw softmax + neighbor mixing -------------------
// W[q,d] = q[q,d] * sum_k softmax_k(q·w_k + w_b)[k] * V[q,k,d]
__global__ __launch_bounds__(256) void kwmix_kernel(
    const float* __restrict__ QP, const float* __restrict__ wk,
    const float* __restrict__ wb, const float* __restrict__ V,
    float* __restrict__ W)
{
  const int wave = threadIdx.x >> 6, lane = threadIdx.x & 63;
  const int q = blockIdx.x*4 + wave;
  float qv[4];
#pragma unroll
  for (int j = 0; j < 4; ++j) qv[j] = QP[(size_t)q*256 + lane + 64*j];
  float logit[8];
#pragma unroll
  for (int k = 0; k < 8; ++k) {
    float p = 0.f;
#pragma unroll
    for (int j = 0; j < 4; ++j) p += qv[j]*wk[k*256 + lane + 64*j];
    for (int off = 32; off; off >>= 1) p += __shfl_xor(p, off);
    logit[k] = p + wb[k];
  }
  float mx = logit[0];
#pragma unroll
  for (int k = 1; k < 8; ++k) mx = fmaxf(mx, logit[k]);
  float e[8]; float s = 0.f;
#pragma unroll
  for (int k = 0; k < 8; ++k) { e[k] = expf(logit[k]-mx); s += e[k]; }
  float inv = 1.f/s;
  float acc[4] = {0.f,0.f,0.f,0.f};
#pragma unroll
  for (int k = 0; k < 8; ++k) {
    float kwv = e[k]*inv;
#pragma unroll
    for (int j = 0; j < 4; ++j)
      acc[j] = fmaf(kwv, V[(size_t)(q*8+k)*256 + lane + 64*j], acc[j]);
  }
#pragma unroll
  for (int j = 0; j < 4; ++j)
    W[(size_t)q*256 + lane + 64*j] = qv[j]*acc[j];
}

// -------------------------- LayerNorm over D=256 (1 wave / row) ------------
__global__ __launch_bounds__(256) void ln_kernel(
    const float* __restrict__ a, const float* __restrict__ b,
    float* __restrict__ out, int rows)
{
  const int wave = threadIdx.x >> 6, lane = threadIdx.x & 63;
  const int row = blockIdx.x*4 + wave;
  if (row >= rows) return;
  float v[4];
#pragma unroll
  for (int j = 0; j < 4; ++j) {
    float x = a[(size_t)row*256 + lane + 64*j];
    if (b) x += b[(size_t)row*256 + lane + 64*j];
    v[j] = x;
  }
  float s = v[0]+v[1]+v[2]+v[3];
  for (int off = 32; off; off >>= 1) s += __shfl_xor(s, off);
  float m = s * (1.0f/256.0f);
  float t = 0.f;
#pragma unroll
  for (int j = 0; j < 4; ++j) { float d = v[j]-m; t += d*d; }
  for (int off = 32; off; off >>= 1) t += __shfl_xor(t, off);
  float r = rsqrtf(t * (1.0f/256.0f) + 1e-5f);
#pragma unroll
  for (int j = 0; j < 4; ++j)
    out[(size_t)row*256 + lane + 64*j] = (v[j]-m)*r;
}

// unsort both paths + residual + LN (in-place on X)
__global__ __launch_bounds__(256) void ln_unsort_kernel(
    const float* __restrict__ OUTL, const int* __restrict__ INV,
    float* __restrict__ X)
{
  const int wave = threadIdx.x >> 6, lane = threadIdx.x & 63;
  const int q = blockIdx.x*4 + wave;
  const int i0 = INV[q], i1 = INV[2048 + q];
  float v[4];
#pragma unroll
  for (int j = 0; j < 4; ++j) {
    int d = lane + 64*j;
    v[j] = X[(size_t)q*256 + d]
         + 0.5f*(OUTL[(size_t)i0*256 + d] + OUTL[(size_t)(2048+i1)*256 + d]);
  }
  float s = v[0]+v[1]+v[2]+v[3];
  for (int off = 32; off; off >>= 1) s += __shfl_xor(s, off);
  float m = s * (1.0f/256.0f);
  float t = 0.f;
#pragma unroll
  for (int j = 0; j < 4; ++j) { float d = v[j]-m; t += d*d; }
  for (int off = 32; off; off >>= 1) t += __shfl_xor(t, off);
  float r = rsqrtf(t * (1.0f/256.0f) + 1e-5f);
#pragma unroll
  for (int j = 0; j < 4; ++j)
    X[(size_t)q*256 + lane + 64*j] = (v[j]-m)*r;
}

// -------------------------- causal depthwise conv (KC=4) + SiLU ------------
__global__ void conv_kernel(const float* __restrict__ PROJ,
    const float* __restrict__ Wc, const float* __restrict__ bc,
    float* __restrict__ XBC)
{
  const int c = threadIdx.x;      // 640
  const int bt = blockIdx.x;      // 4096
  const int t = bt & 2047;
  float acc = bc[c];
#pragma unroll
  for (int j = 0; j < 4; ++j) {
    int d = j - 3;
    if (t + d >= 0)
      acc = fmaf(PROJ[(size_t)(bt + d)*1160 + 512 + c], Wc[c*4+j], acc);
  }
  XBC[(size_t)bt*640 + c] = acc / (1.f + expf(-acc));  // silu
}

// -------------------------- dt softplus + dA -------------------------------
// outputs transposed: Ddt/Dda layout [H][B*T] for coalesced scan reads
__global__ void dta_kernel(const float* __restrict__ PROJ,
    const float* __restrict__ dtb, const float* __restrict__ Alog,
    float* __restrict__ Ddt, float* __restrict__ Dda)
{
  const int i = blockIdx.x*256 + threadIdx.x;   // 32768 = 4096*8
  const int bt = i >> 3, hh = i & 7;
  float x = PROJ[(size_t)bt*1160 + 1152 + hh] + dtb[hh];
  float dt = (x > 20.f) ? x : log1pf(expf(x));
  float A = -expf(Alog[hh]);
  Ddt[hh*4096 + bt] = dt;
  Dda[hh*4096 + bt] = expf(dt * A);
}

// -------------------------- scan pass 1: per-chunk S_c, P_c ----------------
// grid = b(2) * h(8) * chunk(32) = 512 blocks, 64 threads (lane = d)
__global__ __launch_bounds__(64) void scan1_kernel(
    const float* __restrict__ XBC, const float* __restrict__ Ddt,
    const float* __restrict__ Dda, float* __restrict__ SCH, float* __restrict__ PC)
{
  const int blk = blockIdx.x;
  const int c = blk & 31, hh = (blk >> 5) & 7, b = blk >> 8;
  const int lane = threadIdx.x;
  const int t0 = (b << 11) + (c << 6);
  __shared__ float Bsh[64][64];
  __shared__ float Xsh[64][64];
  __shared__ float dAs[64], dts[64];
  // float4 tile staging: 16 iters, each wave covers 4 rows coalesced
#pragma unroll
  for (int it = 0; it < 16; ++it) {
    int idx = it*64 + lane;          // 0..1023
    int t = idx >> 4, c4 = (idx & 15) << 2;
    *(float4*)&Bsh[t][c4] = *(const float4*)&XBC[(size_t)(t0 + t)*640 + 512 + c4];
    *(float4*)&Xsh[t][c4] = *(const float4*)&XBC[(size_t)(t0 + t)*640 + (hh<<6) + c4];
  }
  dAs[lane] = Dda[hh*4096 + t0 + lane];
  dts[lane] = Ddt[hh*4096 + t0 + lane];
  __syncthreads();
  float h[64];
#pragma unroll
  for (int s = 0; s < 64; ++s) h[s] = 0.f;
  float p = 1.f;
  for (int t = 0; t < 64; ++t) {
    const float dA = dAs[t];
    const float u = dts[t]*Xsh[t][lane];
    p *= dA;
    const float4* B4 = (const float4*)&Bsh[t][0];
#pragma unroll
    for (int s4 = 0; s4 < 16; ++s4) {
      float4 bv = B4[s4];
      h[4*s4+0] = fmaf(h[4*s4+0], dA, bv.x*u);
      h[4*s4+1] = fmaf(h[4*s4+1], dA, bv.y*u);
      h[4*s4+2] = fmaf(h[4*s4+2], dA, bv.z*u);
      h[4*s4+3] = fmaf(h[4*s4+3], dA, bv.w*u);
    }
  }
  float* op = SCH + (size_t)blk*4096 + lane*64;
#pragma unroll
  for (int s4 = 0; s4 < 16; ++s4)
    ((float4*)op)[s4] = make_float4(h[4*s4], h[4*s4+1], h[4*s4+2], h[4*s4+3]);
  if (lane == 0) PC[blk] = p;
}

// -------------------------- sequential cross-chunk combine (in-place) ------
// After this, SCH[(bh,c)] holds h_start of chunk c.
__global__ void combine_kernel(float* __restrict__ SCH, const float* __restrict__ PC)
{
  const int tid = blockIdx.x*256 + threadIdx.x;   // 65536
  const int bh = tid >> 12, ds = tid & 4095;
  float h = 0.f;
  for (int cc = 0; cc < 32; ++cc) {
    size_t o = ((size_t)(bh*32 + cc) << 12) + ds;
    float s = SCH[o];
    SCH[o] = h;
    h = fmaf(h, PC[bh*32+cc], s);
  }
}

// -------------------------- scan pass 2: exact recurrence + y --------------
__global__ __launch_bounds__(64) void scan2_kernel(
    const float* __restrict__ XBC, const float* __restrict__ Ddt,
    const float* __restrict__ Dda, const float* __restrict__ HST,
    const float* __restrict__ Dm, float* __restrict__ Yout)
{
  const int blk = blockIdx.x;
  const int c = blk & 31, hh = (blk >> 5) & 7, b = blk >> 8;
  const int lane = threadIdx.x;
  const int t0 = (b << 11) + (c << 6);
  __shared__ float Bsh[64][64];
  __shared__ float Csh[64][64];
  __shared__ float Xsh[64][64];
  __shared__ float dAs[64], dts[64];
#pragma unroll
  for (int it = 0; it < 16; ++it) {
    int idx = it*64 + lane;
    int t = idx >> 4, c4 = (idx & 15) << 2;
    *(float4*)&Bsh[t][c4] = *(const float4*)&XBC[(size_t)(t0 + t)*640 + 512 + c4];
    *(float4*)&Csh[t][c4] = *(const float4*)&XBC[(size_t)(t0 + t)*640 + 576 + c4];
    *(float4*)&Xsh[t][c4] = *(const float4*)&XBC[(size_t)(t0 + t)*640 + (hh<<6) + c4];
  }
  dAs[lane] = Dda[hh*4096 + t0 + lane];
  dts[lane] = Ddt[hh*4096 + t0 + lane];
  const float Dh = Dm[hh];
  float h[64];
  const float4* hp = (const float4*)(HST + (size_t)blk*4096 + lane*64);
#pragma unroll
  for (int s4 = 0; s4 < 16; ++s4) {
    float4 t4 = hp[s4];
    h[4*s4+0]=t4.x; h[4*s4+1]=t4.y; h[4*s4+2]=t4.z; h[4*s4+3]=t4.w;
  }
  __syncthreads();
  for (int t = 0; t < 64; ++t) {
    const float dA = dAs[t];
    const float u = dts[t]*Xsh[t][lane];
    float y = 0.f;
    const float4* B4 = (const float4*)&Bsh[t][0];
    const float4* C4 = (const float4*)&Csh[t][0];
#pragma unroll
    for (int s4 = 0; s4 < 16; ++s4) {
      float4 bv = B4[s4];
      float4 cv = C4[s4];
      h[4*s4+0] = fmaf(h[4*s4+0], dA, bv.x*u); y = fmaf(cv.x, h[4*s4+0], y);
      h[4*s4+1] = fmaf(h[4*s4+1], dA, bv.y*u); y = fmaf(cv.y, h[4*s4+1], y);
      h[4*s4+2] = fmaf(h[4*s4+2], dA, bv.z*u); y = fmaf(cv.z, h[4*s4+2], y);
      h[4*s4+3] = fmaf(h[4*s4+3], dA, bv.w*u); y = fmaf(cv.w, h[4*s4+3], y);
    }
    Yout[(size_t)(t0 + t)*512 + (hh<<6) + lane] = y + Dh*Xsh[t][lane];
  }
}

// -------------------------- gate (silu(z)) + RMSNorm over 512 (in-place) ---
__global__ __launch_bounds__(256) void gaterms_kernel(
    float* __restrict__ Y, const float* __restrict__ PROJ,
    const float* __restrict__ rmsw)
{
  const int wave = threadIdx.x >> 6, lane = threadIdx.x & 63;
  const int row = blockIdx.x*4 + wave;   // 4096
  float v[8]; float ss = 0.f;
#pragma unroll
  for (int j = 0; j < 8; ++j) {
    float y = Y[(size_t)row*512 + lane + 64*j];
    float z = PROJ[(size_t)row*1160 + lane + 64*j];
    float g = y * (z / (1.f + expf(-z)));
    v[j] = g; ss += g*g;
  }
  for (int off = 32; off; off >>= 1) ss += __shfl_xor(ss, off);
  float r = rsqrtf(ss * (1.0f/512.0f) + 1e-5f);
#pragma unroll
  for (int j = 0; j < 8; ++j)
    Y[(size_t)row*512 + lane + 64*j] = v[j] * r * rmsw[lane + 64*j];
}

// ---------------------------------------------------------------------------
extern "C" void kernel_launch(void* const* d_in, const int* in_sizes, int n_in,
                              void* d_out, int out_size, void* d_ws, size_t ws_size,
                              hipStream_t stream)
{
  (void)in_sizes; (void)n_in; (void)out_size; (void)ws_size;
  const float* query = (const float*)d_in[0];
  const float* qpos  = (const float*)d_in[1];
  const float* feats = (const float*)d_in[2];
  const float* spos  = (const float*)d_in[3];
  const float* w_q   = (const float*)d_in[4];
  const float* w_v   = (const float*)d_in[5];
  const float* w_o   = (const float*)d_in[6];
  const float* w_k   = (const float*)d_in[7];
  const float* w_b   = (const float*)d_in[8];
  const float* Win   = (const float*)d_in[9];
  const float* Wconv = (const float*)d_in[10];
  const float* bconv = (const float*)d_in[11];
  const float* Alog  = (const float*)d_in[12];
  const float* Dm    = (const float*)d_in[13];
  const float* dtb   = (const float*)d_in[14];
  const float* rmsw  = (const float*)d_in[15];
  const float* Wout  = (const float*)d_in[16];
  const float* fw1   = (const float*)d_in[17];
  const float* fb1   = (const float*)d_in[18];
  const float* fw2   = (const float*)d_in[19];
  const float* fb2   = (const float*)d_in[20];
  const int*   order = (const int*)d_in[21];
  float* out = (float*)d_out;

  char* ws = (char*)d_ws;
  size_t off = 0;
  auto alloc = [&](size_t bytes) -> void* {
    void* p = ws + off;
    off = (off + bytes + 255) & ~(size_t)255;
    return p;
  };
  int*   IDX = (int*)alloc((size_t)2048*8*4);
  int*   INV = (int*)alloc((size_t)4096*4);
  float* PC  = (float*)alloc((size_t)512*4);
  float* Ddt = (float*)alloc((size_t)4096*8*4);
  float* Dda = (float*)alloc((size_t)4096*8*4);
  float* QP  = (float*)alloc((size_t)2048*256*4);
  float* WB  = (float*)alloc((size_t)2048*256*4);
  float* WO  = (float*)alloc((size_t)2048*256*4);
  float* X   = (float*)alloc((size_t)2048*256*4);
  float* XN  = (float*)alloc((size_t)2048*256*4);
  float* U1  = (float*)alloc((size_t)4096*1160*4);  // V (16MB) | PROJ (19MB)
  float* U2  = (float*)alloc((size_t)4096*640*4);   // XBC (10.5MB) | FFH (8.4MB)
  float* SCH = (float*)alloc((size_t)512*4096*4);   // chunk states (in-place h_start)
  float* Yb  = (float*)alloc((size_t)4096*512*4);
  float* U6  = (float*)alloc((size_t)4096*256*4);   // OUTL | FFO
  float* Vb   = U1;  float* PROJ = U1;
  float* XBC  = U2;  float* FFH  = U2;
  float* OUTL = U6;  float* FFO  = U6;

  // --- stage 1: KNN + aggregation ---
  inv_kernel<<<16, 256, 0, stream>>>(order, INV);
  knn_kernel<<<2048, 256, 0, stream>>>(qpos, spos, IDX);
  gemm_kernel<<<dim3(16,4), 256, 0, stream>>>(query, nullptr, w_q, nullptr, QP, 2048,256,256,0);
  gemm_kernel<<<dim3(128,4), 256, 0, stream>>>(feats, IDX, w_v, nullptr, Vb, 16384,256,256,0);
  kwmix_kernel<<<512, 256, 0, stream>>>(QP, w_k, w_b, Vb, WB);
  gemm_kernel<<<dim3(16,4), 256, 0, stream>>>(WB, nullptr, w_o, nullptr, WO, 2048,256,256,0);
  ln_kernel<<<512, 256, 0, stream>>>(WO, query, X, 2048);

  // --- stage 2: two Mamba2 layers ---
  for (int l = 0; l < 2; ++l) {
    ln_kernel<<<512, 256, 0, stream>>>(X, nullptr, XN, 2048);
    gemm_kernel<<<dim3(32,19), 256, 0, stream>>>(XN, order, Win + (size_t)l*1160*256,
                                                 nullptr, PROJ, 4096,1160,256,0);
    conv_kernel<<<4096, 640, 0, stream>>>(PROJ, Wconv + l*640*4, bconv + l*640, XBC);
    dta_kernel<<<128, 256, 0, stream>>>(PROJ, dtb + l*8, Alog + l*8, Ddt, Dda);
    scan1_kernel<<<512, 64, 0, stream>>>(XBC, Ddt, Dda, SCH, PC);
    combine_kernel<<<256, 256, 0, stream>>>(SCH, PC);
    scan2_kernel<<<512, 64, 0, stream>>>(XBC, Ddt, Dda, SCH, Dm + l*8, Yb);
    gaterms_kernel<<<1024, 256, 0, stream>>>(Yb, PROJ, rmsw + l*512);
    gemm_kernel<<<dim3(32,4), 256, 0, stream>>>(Yb, nullptr, Wout + (size_t)l*256*512,
                                                nullptr, OUTL, 4096,256,512,0);
    ln_unsort_kernel<<<512, 256, 0, stream>>>(OUTL, INV, X);
  }

  // --- stage 3: FFN ---
  gemm_kernel<<<dim3(16,16), 256, 0, stream>>>(X, nullptr, fw1, fb1, FFH, 2048,1024,256,1);
  gemm_kernel<<<dim3(16,4), 256, 0, stream>>>(FFH, nullptr, fw2, fb2, FFO, 2048,256,1024,0);
  ln_kernel<<<512, 256, 0, stream>>>(FFO, X, out, 2048);
}

// Round 6
// 756.447 us; speedup vs baseline: 1.1455x; 1.1455x over previous
//
#include <hip/hip_runtime.h>
#include <cstdint>

// ---------------------------------------------------------------------------
// LaSSMDecoder on MI355X — fp32 baseline, chunked (SSD) Mamba2 scan.
// Round 6: KNN rewritten as wave-level scalar top-8 heap. Round 5's tau
// (wave-min of lane-local 8th-bests) sat near the 30th percentile → gate
// always fired. Now the gate IS the wave-global 8th-best: ballot against
// uniform k7, serial scalar insert of qualifying lanes (~100/wave total).
// ---------------------------------------------------------------------------

// Wave-shared 8-slot sorted list in named registers (uniform values).
// Strict key compare: caller context guarantees later-arriving candidates
// have larger indices, so ties keep the earlier (smaller) index — matches
// jax.lax.top_k stability.
#define KNN_INS_U(ukv, uiv)                                                    \
  do {                                                                         \
    const unsigned int _k = (ukv); const int _v = (uiv);                       \
    const bool a0 = _k < k0;                                                   \
    const bool a1 = _k < k1;                                                   \
    const bool a2 = _k < k2;                                                   \
    const bool a3 = _k < k3;                                                   \
    const bool a4 = _k < k4;                                                   \
    const bool a5 = _k < k5;                                                   \
    const bool a6 = _k < k6;                                                   \
    k7 = a6 ? k6 : _k;              id7 = a6 ? id6 : _v;                       \
    k6 = a5 ? k5 : (a6 ? _k : k6);  id6 = a5 ? id5 : (a6 ? _v : id6);          \
    k5 = a4 ? k4 : (a5 ? _k : k5);  id5 = a4 ? id4 : (a5 ? _v : id5);          \
    k4 = a3 ? k3 : (a4 ? _k : k4);  id4 = a3 ? id3 : (a4 ? _v : id4);          \
    k3 = a2 ? k2 : (a3 ? _k : k3);  id3 = a2 ? id2 : (a3 ? _v : id3);          \
    k2 = a1 ? k1 : (a2 ? _k : k2);  id2 = a1 ? id1 : (a2 ? _v : id2);          \
    k1 = a0 ? k0 : (a1 ? _k : k1);  id1 = a0 ? id0 : (a1 ? _v : id1);          \
    k0 = a0 ? _k : k0;              id0 = a0 ? _v : id0;                       \
  } while (0)

__device__ __forceinline__ bool ulex_less(unsigned int k, int i,
                                          unsigned int kr, int ir) {
  return k < kr || (k == kr && i < ir);
}

// Lexicographic insert for the cross-wave merge; caller pre-qualifies vs slot 7.
#define KNN_INS_ULEX(ukv, uiv)                                                 \
  do {                                                                         \
    const unsigned int _k = (ukv); const int _v = (uiv);                       \
    const bool a0 = ulex_less(_k, _v, k0, id0);                                \
    const bool a1 = ulex_less(_k, _v, k1, id1);                                \
    const bool a2 = ulex_less(_k, _v, k2, id2);                                \
    const bool a3 = ulex_less(_k, _v, k3, id3);                                \
    const bool a4 = ulex_less(_k, _v, k4, id4);                                \
    const bool a5 = ulex_less(_k, _v, k5, id5);                                \
    const bool a6 = ulex_less(_k, _v, k6, id6);                                \
    k7 = a6 ? k6 : _k;              id7 = a6 ? id6 : _v;                       \
    k6 = a5 ? k5 : (a6 ? _k : k6);  id6 = a5 ? id5 : (a6 ? _v : id6);          \
    k5 = a4 ? k4 : (a5 ? _k : k5);  id5 = a4 ? id4 : (a5 ? _v : id5);          \
    k4 = a3 ? k3 : (a4 ? _k : k4);  id4 = a3 ? id3 : (a4 ? _v : id4);          \
    k3 = a2 ? k2 : (a3 ? _k : k3);  id3 = a2 ? id2 : (a3 ? _v : id3);          \
    k2 = a1 ? k1 : (a2 ? _k : k2);  id2 = a1 ? id1 : (a2 ? _v : id2);          \
    k1 = a0 ? k0 : (a1 ? _k : k1);  id1 = a0 ? id0 : (a1 ? _v : id1);          \
    k0 = a0 ? _k : k0;              id0 = a0 ? _v : id0;                       \
  } while (0)

#define KNN_RESET_U()                                                          \
  do {                                                                         \
    k0=k1=k2=k3=k4=k5=k6=k7 = 0xFFFFFFFFu;                                     \
    id0=id1=id2=id3=id4=id5=id6=id7 = 0x7fffffff;                              \
  } while (0)

// -------------------------- prep: pack (sx,sy,sz,|s|^2) as float4 ----------
__global__ void prep_kernel(const float* __restrict__ spos,
                            float4* __restrict__ P4)
{
#pragma clang fp contract(off)
  const int n = blockIdx.x*256 + threadIdx.x;
  if (n < 32768) {
    const float sx = spos[n*3+0], sy = spos[n*3+1], sz = spos[n*3+2];
    P4[n] = make_float4(sx, sy, sz, sx*sx + sy*sy + sz*sz);
  }
}

// -------------------------- KNN (top-8 by squared distance) ----------------
// 1 block / query; 4 waves; each wave keeps ONE shared top-8 (uniform regs).
__global__ __launch_bounds__(256) void knn_kernel(
    const float* __restrict__ qpos, const float4* __restrict__ P4,
    int* __restrict__ idx_out)
{
#pragma clang fp contract(off)
  __shared__ unsigned int skey[32];
  __shared__ int          sidx[32];
  const int q = blockIdx.x, tid = threadIdx.x;
  const int wave = tid >> 6, lane = tid & 63;
  const float qx = qpos[q*3+0], qy = qpos[q*3+1], qz = qpos[q*3+2];
  const float qq = qx*qx + qy*qy + qz*qz;
  unsigned int k0,k1,k2,k3,k4,k5,k6,k7;
  int          id0,id1,id2,id3,id4,id5,id6,id7;
  KNN_RESET_U();
  const int base = wave << 13;              // 8192 points per wave
  for (int it = 0; it < 128; ++it) {
    const int nb = base + (it << 6);
    const float4 p = P4[nb + lane];
    const float dot = qx*p.x + qy*p.y + qz*p.z;
    const float d2 = (qq + p.w) - 2.0f*dot;   // reference's exact formula
    // monotone float->uint key (handles negatives too)
    unsigned int u = __float_as_uint(d2);
    u ^= (unsigned int)((int)u >> 31) | 0x80000000u;
    unsigned long long m = __ballot(u < k7);
    if (m) {
      do {
        const int l = __ffsll(m) - 1;
        m &= m - 1;
        const unsigned int uk = (unsigned int)__shfl((int)u, l);
        if (uk < k7) {                        // k7 shrinks within the batch
          KNN_INS_U(uk, nb + l);
        }
      } while (m);
    }
  }
  if (lane == 0) {
    skey[wave*8+0]=k0; skey[wave*8+1]=k1; skey[wave*8+2]=k2; skey[wave*8+3]=k3;
    skey[wave*8+4]=k4; skey[wave*8+5]=k5; skey[wave*8+6]=k6; skey[wave*8+7]=k7;
    sidx[wave*8+0]=id0; sidx[wave*8+1]=id1; sidx[wave*8+2]=id2; sidx[wave*8+3]=id3;
    sidx[wave*8+4]=id4; sidx[wave*8+5]=id5; sidx[wave*8+6]=id6; sidx[wave*8+7]=id7;
  }
  __syncthreads();
  if (tid == 0) {
    KNN_RESET_U();
    for (int s = 0; s < 32; ++s) {
      const unsigned int uk = skey[s];
      const int          ui = sidx[s];
      if (ulex_less(uk, ui, k7, id7)) KNN_INS_ULEX(uk, ui);
    }
    idx_out[q*8+0]=id0; idx_out[q*8+1]=id1; idx_out[q*8+2]=id2; idx_out[q*8+3]=id3;
    idx_out[q*8+4]=id4; idx_out[q*8+5]=id5; idx_out[q*8+6]=id6; idx_out[q*8+7]=id7;
  }
}

// -------------------------- inverse permutation ----------------------------
__global__ void inv_kernel(const int* __restrict__ order, int* __restrict__ inv)
{
  int i = blockIdx.x*blockDim.x + threadIdx.x;
  if (i < 4096) { int b = i >> 11, t = i & 2047; inv[(b<<11) + order[i]] = t; }
}

// -------------------------- generic tiled GEMM: Y = act(A[rowmap]@Wt^T + b) -
// A: [*, Kd] rows selected by rowmap (nullptr = identity); Wt: [Nn, Kd]
// act: 0 = none, 1 = exact gelu
__global__ __launch_bounds__(256) void gemm_kernel(
    const float* __restrict__ A, const int* __restrict__ rowmap,
    const float* __restrict__ Wt, const float* __restrict__ bias,
    float* __restrict__ Y, int M, int Nn, int Kd, int act)
{
  __shared__ float As[16][128];
  __shared__ float Ws[16][64];
  const int tid = threadIdx.x;
  const int bm = blockIdx.x, bn = blockIdx.y;
  const int tx = tid & 15, ty = tid >> 4;          // 16 x 16 thread grid
  const int ar = tid >> 1, ac = (tid & 1) << 3;    // A-tile load map (128x16)
  const int wr = tid >> 2, wc = (tid & 3) << 2;    // W-tile load map (64x16)
  int arow = bm*128 + ar;
  int asrc = rowmap ? rowmap[arow] : arow;
  const float* Arow = A + (size_t)asrc * Kd;
  int wrow = bn*64 + wr;
  const float* Wrow = (wrow < Nn) ? (Wt + (size_t)wrow * Kd) : nullptr;
  float acc[8][4];
#pragma unroll
  for (int i = 0; i < 8; ++i)
#pragma unroll
    for (int j = 0; j < 4; ++j) acc[i][j] = 0.f;
  for (int k0 = 0; k0 < Kd; k0 += 16) {
    float4 a0 = *(const float4*)(Arow + k0 + ac);
    float4 a1 = *(const float4*)(Arow + k0 + ac + 4);
    float4 w0 = Wrow ? *(const float4*)(Wrow + k0 + wc) : make_float4(0.f,0.f,0.f,0.f);
    As[ac+0][ar] = a0.x; As[ac+1][ar] = a0.y; As[ac+2][ar] = a0.z; As[ac+3][ar] = a0.w;
    As[ac+4][ar] = a1.x; As[ac+5][ar] = a1.y; As[ac+6][ar] = a1.z; As[ac+7][ar] = a1.w;
    Ws[wc+0][wr] = w0.x; Ws[wc+1][wr] = w0.y; Ws[wc+2][wr] = w0.z; Ws[wc+3][wr] = w0.w;
    __syncthreads();
#pragma unroll
    for (int k = 0; k < 16; ++k) {
      float4 aa0 = *(const float4*)&As[k][ty*8];
      float4 aa1 = *(const float4*)&As[k][ty*8+4];
      float4 bb  = *(const float4*)&Ws[k][tx*4];
      float am[8] = {aa0.x,aa0.y,aa0.z,aa0.w,aa1.x,aa1.y,aa1.z,aa1.w};
      float bv[4] = {bb.x,bb.y,bb.z,bb.w};
#pragma unroll
      for (int i = 0; i < 8; ++i)
#pragma unroll
        for (int j = 0; j < 4; ++j)
          acc[i][j] = fmaf(am[i], bv[j], acc[i][j]);
    }
    __syncthreads();
  }
#pragma unroll
  for (int i = 0; i < 8; ++i) {
    int m = bm*128 + ty*8 + i;   // all M here are multiples of 128
#pragma unroll
    for (int j = 0; j < 4; ++j) {
      int n = bn*64 + tx*4 + j;
      if (n < Nn) {
        float v = acc[i][j];
        if (bias) v += bias[n];
        if (act == 1) v = 0.5f*v*(1.f + erff(v*0.7071067811865475f));
        Y[(size_t)m*Nn + n] = v;
      }
    }
  }
}

// -------------------------- kw softmax + neighbor mixing -------------------
// W[q,d] = q[q,d] * sum_k softmax_k(q·w_k + w_b)[k] * V[q,k,d]
__global__ __launch_bounds__(256) void kwmix_kernel(
    const float* __restrict__ QP, const float* __restrict__ wk,
    const float* __restrict__ wb, const float* __restrict__ V,
    float* __restrict__ W)
{
  const int wave = threadIdx.x >> 6, lane = threadIdx.x & 63;
  const int q = blockIdx.x*4 + wave;
  float qv[4];
#pragma unroll
  for (int j = 0; j < 4; ++j) qv[j] = QP[(size_t)q*256 + lane + 64*j];
  float logit[8];
#pragma unroll
  for (int k = 0; k < 8; ++k) {
    float p = 0.f;
#pragma unroll
    for (int j = 0; j < 4; ++j) p += qv[j]*wk[k*256 + lane + 64*j];
    for (int off = 32; off; off >>= 1) p += __shfl_xor(p, off);
    logit[k] = p + wb[k];
  }
  float mx = logit[0];
#pragma unroll
  for (int k = 1; k < 8; ++k) mx = fmaxf(mx, logit[k]);
  float e[8]; float s = 0.f;
#pragma unroll
  for (int k = 0; k < 8; ++k) { e[k] = expf(logit[k]-mx); s += e[k]; }
  float inv = 1.f/s;
  float acc[4] = {0.f,0.f,0.f,0.f};
#pragma unroll
  for (int k = 0; k < 8; ++k) {
    float kwv = e[k]*inv;
#pragma unroll
    for (int j = 0; j < 4; ++j)
      acc[j] = fmaf(kwv, V[(size_t)(q*8+k)*256 + lane + 64*j], acc[j]);
  }
#pragma unroll
  for (int j = 0; j < 4; ++j)
    W[(size_t)q*256 + lane + 64*j] = qv[j]*acc[j];
}

// -------------------------- LayerNorm over D=256 (1 wave / row) ------------
__global__ __launch_bounds__(256) void ln_kernel(
    const float* __restrict__ a, const float* __restrict__ b,
    float* __restrict__ out, int rows)
{
  const int wave = threadIdx.x >> 6, lane = threadIdx.x & 63;
  const int row = blockIdx.x*4 + wave;
  if (row >= rows) return;
  float v[4];
#pragma unroll
  for (int j = 0; j < 4; ++j) {
    float x = a[(size_t)row*256 + lane + 64*j];
    if (b) x += b[(size_t)row*256 + lane + 64*j];
    v[j] = x;
  }
  float s = v[0]+v[1]+v[2]+v[3];
  for (int off = 32; off; off >>= 1) s += __shfl_xor(s, off);
  float m = s * (1.0f/256.0f);
  float t = 0.f;
#pragma unroll
  for (int j = 0; j < 4; ++j) { float d = v[j]-m; t += d*d; }
  for (int off = 32; off; off >>= 1) t += __shfl_xor(t, off);
  float r = rsqrtf(t * (1.0f/256.0f) + 1e-5f);
#pragma unroll
  for (int j = 0; j < 4; ++j)
    out[(size_t)row*256 + lane + 64*j] = (v[j]-m)*r;
}

// unsort both paths + residual + LN (in-place on X)
__global__ __launch_bounds__(256) void ln_unsort_kernel(
    const float* __restrict__ OUTL, const int* __restrict__ INV,
    float* __restrict__ X)
{
  const int wave = threadIdx.x >> 6, lane = threadIdx.x & 63;
  const int q = blockIdx.x*4 + wave;
  const int i0 = INV[q], i1 = INV[2048 + q];
  float v[4];
#pragma unroll
  for (int j = 0; j < 4; ++j) {
    int d = lane + 64*j;
    v[j] = X[(size_t)q*256 + d]
         + 0.5f*(OUTL[(size_t)i0*256 + d] + OUTL[(size_t)(2048+i1)*256 + d]);
  }
  float s = v[0]+v[1]+v[2]+v[3];
  for (int off = 32; off; off >>= 1) s += __shfl_xor(s, off);
  float m = s * (1.0f/256.0f);
  float t = 0.f;
#pragma unroll
  for (int j = 0; j < 4; ++j) { float d = v[j]-m; t += d*d; }
  for (int off = 32; off; off >>= 1) t += __shfl_xor(t, off);
  float r = rsqrtf(t * (1.0f/256.0f) + 1e-5f);
#pragma unroll
  for (int j = 0; j < 4; ++j)
    X[(size_t)q*256 + lane + 64*j] = (v[j]-m)*r;
}

// -------------------------- causal depthwise conv (KC=4) + SiLU ------------
__global__ void conv_kernel(const float* __restrict__ PROJ,
    const float* __restrict__ Wc, const float* __restrict__ bc,
    float* __restrict__ XBC)
{
  const int c = threadIdx.x;      // 640
  const int bt = blockIdx.x;      // 4096
  const int t = bt & 2047;
  float acc = bc[c];
#pragma unroll
  for (int j = 0; j < 4; ++j) {
    int d = j - 3;
    if (t + d >= 0)
      acc = fmaf(PROJ[(size_t)(bt + d)*1160 + 512 + c], Wc[c*4+j], acc);
  }
  XBC[(size_t)bt*640 + c] = acc / (1.f + expf(-acc));  // silu
}

// -------------------------- dt softplus + dA -------------------------------
// outputs transposed: Ddt/Dda layout [H][B*T] for coalesced scan reads
__global__ void dta_kernel(const float* __restrict__ PROJ,
    const float* __restrict__ dtb, const float* __restrict__ Alog,
    float* __restrict__ Ddt, float* __restrict__ Dda)
{
  const int i = blockIdx.x*256 + threadIdx.x;   // 32768 = 4096*8
  const int bt = i >> 3, hh = i & 7;
  float x = PROJ[(size_t)bt*1160 + 1152 + hh] + dtb[hh];
  float dt = (x > 20.f) ? x : log1pf(expf(x));
  float A = -expf(Alog[hh]);
  Ddt[hh*4096 + bt] = dt;
  Dda[hh*4096 + bt] = expf(dt * A);
}

// -------------------------- scan pass 1: per-chunk S_c, P_c ----------------
// grid = b(2) * h(8) * chunk(32) = 512 blocks, 64 threads (lane = d)
__global__ __launch_bounds__(64) void scan1_kernel(
    const float* __restrict__ XBC, const float* __restrict__ Ddt,
    const float* __restrict__ Dda, float* __restrict__ SCH, float* __restrict__ PC)
{
  const int blk = blockIdx.x;
  const int c = blk & 31, hh = (blk >> 5) & 7, b = blk >> 8;
  const int lane = threadIdx.x;
  const int t0 = (b << 11) + (c << 6);
  __shared__ float Bsh[64][64];
  __shared__ float Xsh[64][64];
  __shared__ float dAs[64], dts[64];
  // float4 tile staging: 16 iters, each wave covers 4 rows coalesced
#pragma unroll
  for (int it = 0; it < 16; ++it) {
    int idx = it*64 + lane;          // 0..1023
    int t = idx >> 4, c4 = (idx & 15) << 2;
    *(float4*)&Bsh[t][c4] = *(const float4*)&XBC[(size_t)(t0 + t)*640 + 512 + c4];
    *(float4*)&Xsh[t][c4] = *(const float4*)&XBC[(size_t)(t0 + t)*640 + (hh<<6) + c4];
  }
  dAs[lane] = Dda[hh*4096 + t0 + lane];
  dts[lane] = Ddt[hh*4096 + t0 + lane];
  __syncthreads();
  float h[64];
#pragma unroll
  for (int s = 0; s < 64; ++s) h[s] = 0.f;
  float p = 1.f;
  for (int t = 0; t < 64; ++t) {
    const float dA = dAs[t];
    const float u = dts[t]*Xsh[t][lane];
    p *= dA;
    const float4* B4 = (const float4*)&Bsh[t][0];
#pragma unroll
    for (int s4 = 0; s4 < 16; ++s4) {
      float4 bv = B4[s4];
      h[4*s4+0] = fmaf(h[4*s4+0], dA, bv.x*u);
      h[4*s4+1] = fmaf(h[4*s4+1], dA, bv.y*u);
      h[4*s4+2] = fmaf(h[4*s4+2], dA, bv.z*u);
      h[4*s4+3] = fmaf(h[4*s4+3], dA, bv.w*u);
    }
  }
  float* op = SCH + (size_t)blk*4096 + lane*64;
#pragma unroll
  for (int s4 = 0; s4 < 16; ++s4)
    ((float4*)op)[s4] = make_float4(h[4*s4], h[4*s4+1], h[4*s4+2], h[4*s4+3]);
  if (lane == 0) PC[blk] = p;
}

// -------------------------- sequential cross-chunk combine (in-place) ------
// After this, SCH[(bh,c)] holds h_start of chunk c.
__global__ void combine_kernel(float* __restrict__ SCH, const float* __restrict__ PC)
{
  const int tid = blockIdx.x*256 + threadIdx.x;   // 65536
  const int bh = tid >> 12, ds = tid & 4095;
  float h = 0.f;
  for (int cc = 0; cc < 32; ++cc) {
    size_t o = ((size_t)(bh*32 + cc) << 12) + ds;
    float s = SCH[o];
    SCH[o] = h;
    h = fmaf(h, PC[bh*32+cc], s);
  }
}

// -------------------------- scan pass 2: exact recurrence + y --------------
__global__ __launch_bounds__(64) void scan2_kernel(
    const float* __restrict__ XBC, const float* __restrict__ Ddt,
    const float* __restrict__ Dda, const float* __restrict__ HST,
    const float* __restrict__ Dm, float* __restrict__ Yout)
{
  const int blk = blockIdx.x;
  const int c = blk & 31, hh = (blk >> 5) & 7, b = blk >> 8;
  const int lane = threadIdx.x;
  const int t0 = (b << 11) + (c << 6);
  __shared__ float Bsh[64][64];
  __shared__ float Csh[64][64];
  __shared__ float Xsh[64][64];
  __shared__ float dAs[64], dts[64];
#pragma unroll
  for (int it = 0; it < 16; ++it) {
    int idx = it*64 + lane;
    int t = idx >> 4, c4 = (idx & 15) << 2;
    *(float4*)&Bsh[t][c4] = *(const float4*)&XBC[(size_t)(t0 + t)*640 + 512 + c4];
    *(float4*)&Csh[t][c4] = *(const float4*)&XBC[(size_t)(t0 + t)*640 + 576 + c4];
    *(float4*)&Xsh[t][c4] = *(const float4*)&XBC[(size_t)(t0 + t)*640 + (hh<<6) + c4];
  }
  dAs[lane] = Dda[hh*4096 + t0 + lane];
  dts[lane] = Ddt[hh*4096 + t0 + lane];
  const float Dh = Dm[hh];
  float h[64];
  const float4* hp = (const float4*)(HST + (size_t)blk*4096 + lane*64);
#pragma unroll
  for (int s4 = 0; s4 < 16; ++s4) {
    float4 t4 = hp[s4];
    h[4*s4+0]=t4.x; h[4*s4+1]=t4.y; h[4*s4+2]=t4.z; h[4*s4+3]=t4.w;
  }
  __syncthreads();
  for (int t = 0; t < 64; ++t) {
    const float dA = dAs[t];
    const float u = dts[t]*Xsh[t][lane];
    float y = 0.f;
    const float4* B4 = (const float4*)&Bsh[t][0];
    const float4* C4 = (const float4*)&Csh[t][0];
#pragma unroll
    for (int s4 = 0; s4 < 16; ++s4) {
      float4 bv = B4[s4];
      float4 cv = C4[s4];
      h[4*s4+0] = fmaf(h[4*s4+0], dA, bv.x*u); y = fmaf(cv.x, h[4*s4+0], y);
      h[4*s4+1] = fmaf(h[4*s4+1], dA, bv.y*u); y = fmaf(cv.y, h[4*s4+1], y);
      h[4*s4+2] = fmaf(h[4*s4+2], dA, bv.z*u); y = fmaf(cv.z, h[4*s4+2], y);
      h[4*s4+3] = fmaf(h[4*s4+3], dA, bv.w*u); y = fmaf(cv.w, h[4*s4+3], y);
    }
    Yout[(size_t)(t0 + t)*512 + (hh<<6) + lane] = y + Dh*Xsh[t][lane];
  }
}

// -------------------------- gate (silu(z)) + RMSNorm over 512 (in-place) ---
__global__ __launch_bounds__(256) void gaterms_kernel(
    float* __restrict__ Y, const float* __restrict__ PROJ,
    const float* __restrict__ rmsw)
{
  const int wave = threadIdx.x >> 6, lane = threadIdx.x & 63;
  const int row = blockIdx.x*4 + wave;   // 4096
  float v[8]; float ss = 0.f;
#pragma unroll
  for (int j = 0; j < 8; ++j) {
    float y = Y[(size_t)row*512 + lane + 64*j];
    float z = PROJ[(size_t)row*1160 + lane + 64*j];
    float g = y * (z / (1.f + expf(-z)));
    v[j] = g; ss += g*g;
  }
  for (int off = 32; off; off >>= 1) ss += __shfl_xor(ss, off);
  float r = rsqrtf(ss * (1.0f/512.0f) + 1e-5f);
#pragma unroll
  for (int j = 0; j < 8; ++j)
    Y[(size_t)row*512 + lane + 64*j] = v[j] * r * rmsw[lane + 64*j];
}

// ---------------------------------------------------------------------------
extern "C" void kernel_launch(void* const* d_in, const int* in_sizes, int n_in,
                              void* d_out, int out_size, void* d_ws, size_t ws_size,
                              hipStream_t stream)
{
  (void)in_sizes; (void)n_in; (void)out_size; (void)ws_size;
  const float* query = (const float*)d_in[0];
  const float* qpos  = (const float*)d_in[1];
  const float* feats = (const float*)d_in[2];
  const float* spos  = (const float*)d_in[3];
  const float* w_q   = (const float*)d_in[4];
  const float* w_v   = (const float*)d_in[5];
  const float* w_o   = (const float*)d_in[6];
  const float* w_k   = (const float*)d_in[7];
  const float* w_b   = (const float*)d_in[8];
  const float* Win   = (const float*)d_in[9];
  const float* Wconv = (const float*)d_in[10];
  const float* bconv = (const float*)d_in[11];
  const float* Alog  = (const float*)d_in[12];
  const float* Dm    = (const float*)d_in[13];
  const float* dtb   = (const float*)d_in[14];
  const float* rmsw  = (const float*)d_in[15];
  const float* Wout  = (const float*)d_in[16];
  const float* fw1   = (const float*)d_in[17];
  const float* fb1   = (const float*)d_in[18];
  const float* fw2   = (const float*)d_in[19];
  const float* fb2   = (const float*)d_in[20];
  const int*   order = (const int*)d_in[21];
  float* out = (float*)d_out;

  char* ws = (char*)d_ws;
  size_t off = 0;
  auto alloc = [&](size_t bytes) -> void* {
    void* p = ws + off;
    off = (off + bytes + 255) & ~(size_t)255;
    return p;
  };
  int*   IDX = (int*)alloc((size_t)2048*8*4);
  int*   INV = (int*)alloc((size_t)4096*4);
  float* PC  = (float*)alloc((size_t)512*4);
  float4* P4 = (float4*)alloc((size_t)32768*16);
  float* Ddt = (float*)alloc((size_t)4096*8*4);
  float* Dda = (float*)alloc((size_t)4096*8*4);
  float* QP  = (float*)alloc((size_t)2048*256*4);
  float* WB  = (float*)alloc((size_t)2048*256*4);
  float* WO  = (float*)alloc((size_t)2048*256*4);
  float* X   = (float*)alloc((size_t)2048*256*4);
  float* XN  = (float*)alloc((size_t)2048*256*4);
  float* U1  = (float*)alloc((size_t)4096*1160*4);  // V (16MB) | PROJ (19MB)
  float* U2  = (float*)alloc((size_t)4096*640*4);   // XBC (10.5MB) | FFH (8.4MB)
  float* SCH = (float*)alloc((size_t)512*4096*4);   // chunk states (in-place h_start)
  float* Yb  = (float*)alloc((size_t)4096*512*4);
  float* U6  = (float*)alloc((size_t)4096*256*4);   // OUTL | FFO
  float* Vb   = U1;  float* PROJ = U1;
  float* XBC  = U2;  float* FFH  = U2;
  float* OUTL = U6;  float* FFO  = U6;

  // --- stage 1: KNN + aggregation ---
  inv_kernel<<<16, 256, 0, stream>>>(order, INV);
  prep_kernel<<<128, 256, 0, stream>>>(spos, P4);
  knn_kernel<<<2048, 256, 0, stream>>>(qpos, P4, IDX);
  gemm_kernel<<<dim3(16,4), 256, 0, stream>>>(query, nullptr, w_q, nullptr, QP, 2048,256,256,0);
  gemm_kernel<<<dim3(128,4), 256, 0, stream>>>(feats, IDX, w_v, nullptr, Vb, 16384,256,256,0);
  kwmix_kernel<<<512, 256, 0, stream>>>(QP, w_k, w_b, Vb, WB);
  gemm_kernel<<<dim3(16,4), 256, 0, stream>>>(WB, nullptr, w_o, nullptr, WO, 2048,256,256,0);
  ln_kernel<<<512, 256, 0, stream>>>(WO, query, X, 2048);

  // --- stage 2: two Mamba2 layers ---
  for (int l = 0; l < 2; ++l) {
    ln_kernel<<<512, 256, 0, stream>>>(X, nullptr, XN, 2048);
    gemm_kernel<<<dim3(32,19), 256, 0, stream>>>(XN, order, Win + (size_t)l*1160*256,
                                                 nullptr, PROJ, 4096,1160,256,0);
    conv_kernel<<<4096, 640, 0, stream>>>(PROJ, Wconv + l*640*4, bconv + l*640, XBC);
    dta_kernel<<<128, 256, 0, stream>>>(PROJ, dtb + l*8, Alog + l*8, Ddt, Dda);
    scan1_kernel<<<512, 64, 0, stream>>>(XBC, Ddt, Dda, SCH, PC);
    combine_kernel<<<256, 256, 0, stream>>>(SCH, PC);
    scan2_kernel<<<512, 64, 0, stream>>>(XBC, Ddt, Dda, SCH, Dm + l*8, Yb);
    gaterms_kernel<<<1024, 256, 0, stream>>>(Yb, PROJ, rmsw + l*512);
    gemm_kernel<<<dim3(32,4), 256, 0, stream>>>(Yb, nullptr, Wout + (size_t)l*256*512,
                                                nullptr, OUTL, 4096,256,512,0);
    ln_unsort_kernel<<<512, 256, 0, stream>>>(OUTL, INV, X);
  }

  // --- stage 3: FFN ---
  gemm_kernel<<<dim3(16,16), 256, 0, stream>>>(X, nullptr, fw1, fb1, FFH, 2048,1024,256,1);
  gemm_kernel<<<dim3(16,4), 256, 0, stream>>>(FFH, nullptr, fw2, fb2, FFO, 2048,256,1024,0);
  ln_kernel<<<512, 256, 0, stream>>>(FFO, X, out, 2048);
}

// Round 8
// 600.959 us; speedup vs baseline: 1.4419x; 1.2587x over previous
//
#include <hip/hip_runtime.h>
#include <cstdint>

// ---------------------------------------------------------------------------
// LaSSMDecoder on MI355X — Round 8: MFMA GEMMs with PRE-CONVERTED 2-term bf16
// split planes (round-7 converted inside the K-loop → would be VALU-bound;
// cvt_kernel now runs once per operand). 3 MFMA products, fp32 accumulate.
// KNN/scan structure unchanged from round 6 (knn 94 µs, wave-level heap).
// ---------------------------------------------------------------------------

typedef __attribute__((ext_vector_type(8))) short bf16x8;
typedef __attribute__((ext_vector_type(4))) float f32x4;
typedef unsigned short ushort_t;

__device__ __forceinline__ unsigned short f2bf(float f) {
  unsigned int u = __float_as_uint(f);
  u += 0x7fff + ((u >> 16) & 1);        // RNE
  return (unsigned short)(u >> 16);
}
__device__ __forceinline__ float bf2f(unsigned short h) {
  return __uint_as_float(((unsigned int)h) << 16);
}

// -------------------------- fp32 -> (hi, lo) bf16 planes -------------------
__global__ __launch_bounds__(256) void cvt_kernel(
    const float* __restrict__ src, unsigned short* __restrict__ hi,
    unsigned short* __restrict__ lo, int n4)
{
  const int i = blockIdx.x*256 + threadIdx.x;
  if (i < n4) {
    const float4 v = ((const float4*)src)[i];
    const unsigned short h0=f2bf(v.x), h1=f2bf(v.y), h2=f2bf(v.z), h3=f2bf(v.w);
    const unsigned short l0=f2bf(v.x-bf2f(h0)), l1=f2bf(v.y-bf2f(h1)),
                         l2=f2bf(v.z-bf2f(h2)), l3=f2bf(v.w-bf2f(h3));
    ((uint2*)hi)[i] = make_uint2((unsigned)h0 | ((unsigned)h1<<16),
                                 (unsigned)h2 | ((unsigned)h3<<16));
    ((uint2*)lo)[i] = make_uint2((unsigned)l0 | ((unsigned)l1<<16),
                                 (unsigned)l2 | ((unsigned)l3<<16));
  }
}

// ---------------- wave-level top-8 heap helpers (round 6, unchanged) -------
#define KNN_INS_U(ukv, uiv)                                                    \
  do {                                                                         \
    const unsigned int _k = (ukv); const int _v = (uiv);                       \
    const bool a0 = _k < k0;                                                   \
    const bool a1 = _k < k1;                                                   \
    const bool a2 = _k < k2;                                                   \
    const bool a3 = _k < k3;                                                   \
    const bool a4 = _k < k4;                                                   \
    const bool a5 = _k < k5;                                                   \
    const bool a6 = _k < k6;                                                   \
    k7 = a6 ? k6 : _k;              id7 = a6 ? id6 : _v;                       \
    k6 = a5 ? k5 : (a6 ? _k : k6);  id6 = a5 ? id5 : (a6 ? _v : id6);          \
    k5 = a4 ? k4 : (a5 ? _k : k5);  id5 = a4 ? id4 : (a5 ? _v : id5);          \
    k4 = a3 ? k3 : (a4 ? _k : k4);  id4 = a3 ? id3 : (a4 ? _v : id4);          \
    k3 = a2 ? k2 : (a3 ? _k : k3);  id3 = a2 ? id2 : (a3 ? _v : id3);          \
    k2 = a1 ? k1 : (a2 ? _k : k2);  id2 = a1 ? id1 : (a2 ? _v : id2);          \
    k1 = a0 ? k0 : (a1 ? _k : k1);  id1 = a0 ? id0 : (a1 ? _v : id1);          \
    k0 = a0 ? _k : k0;              id0 = a0 ? _v : id0;                       \
  } while (0)

__device__ __forceinline__ bool ulex_less(unsigned int k, int i,
                                          unsigned int kr, int ir) {
  return k < kr || (k == kr && i < ir);
}

#define KNN_INS_ULEX(ukv, uiv)                                                 \
  do {                                                                         \
    const unsigned int _k = (ukv); const int _v = (uiv);                       \
    const bool a0 = ulex_less(_k, _v, k0, id0);                                \
    const bool a1 = ulex_less(_k, _v, k1, id1);                                \
    const bool a2 = ulex_less(_k, _v, k2, id2);                                \
    const bool a3 = ulex_less(_k, _v, k3, id3);                                \
    const bool a4 = ulex_less(_k, _v, k4, id4);                                \
    const bool a5 = ulex_less(_k, _v, k5, id5);                                \
    const bool a6 = ulex_less(_k, _v, k6, id6);                                \
    k7 = a6 ? k6 : _k;              id7 = a6 ? id6 : _v;                       \
    k6 = a5 ? k5 : (a6 ? _k : k6);  id6 = a5 ? id5 : (a6 ? _v : id6);          \
    k5 = a4 ? k4 : (a5 ? _k : k5);  id5 = a4 ? id4 : (a5 ? _v : id5);          \
    k4 = a3 ? k3 : (a4 ? _k : k4);  id4 = a3 ? id3 : (a4 ? _v : id4);          \
    k3 = a2 ? k2 : (a3 ? _k : k3);  id3 = a2 ? id2 : (a3 ? _v : id3);          \
    k2 = a1 ? k1 : (a2 ? _k : k2);  id2 = a1 ? id1 : (a2 ? _v : id2);          \
    k1 = a0 ? k0 : (a1 ? _k : k1);  id1 = a0 ? id0 : (a1 ? _v : id1);          \
    k0 = a0 ? _k : k0;              id0 = a0 ? _v : id0;                       \
  } while (0)

#define KNN_RESET_U()                                                          \
  do {                                                                         \
    k0=k1=k2=k3=k4=k5=k6=k7 = 0xFFFFFFFFu;                                     \
    id0=id1=id2=id3=id4=id5=id6=id7 = 0x7fffffff;                              \
  } while (0)

// -------------------------- prep: pack (sx,sy,sz,|s|^2) as float4 ----------
__global__ void prep_kernel(const float* __restrict__ spos,
                            float4* __restrict__ P4)
{
#pragma clang fp contract(off)
  const int n = blockIdx.x*256 + threadIdx.x;
  if (n < 32768) {
    const float sx = spos[n*3+0], sy = spos[n*3+1], sz = spos[n*3+2];
    P4[n] = make_float4(sx, sy, sz, sx*sx + sy*sy + sz*sz);
  }
}

// -------------------------- KNN (top-8 by squared distance) ----------------
__global__ __launch_bounds__(256) void knn_kernel(
    const float* __restrict__ qpos, const float4* __restrict__ P4,
    int* __restrict__ idx_out)
{
#pragma clang fp contract(off)
  __shared__ unsigned int skey[32];
  __shared__ int          sidx[32];
  const int q = blockIdx.x, tid = threadIdx.x;
  const int wave = tid >> 6, lane = tid & 63;
  const float qx = qpos[q*3+0], qy = qpos[q*3+1], qz = qpos[q*3+2];
  const float qq = qx*qx + qy*qy + qz*qz;
  unsigned int k0,k1,k2,k3,k4,k5,k6,k7;
  int          id0,id1,id2,id3,id4,id5,id6,id7;
  KNN_RESET_U();
  const int base = wave << 13;              // 8192 points per wave
  for (int it = 0; it < 128; ++it) {
    const int nb = base + (it << 6);
    const float4 p = P4[nb + lane];
    const float dot = qx*p.x + qy*p.y + qz*p.z;
    const float d2 = (qq + p.w) - 2.0f*dot;   // reference's exact formula
    unsigned int u = __float_as_uint(d2);
    u ^= (unsigned int)((int)u >> 31) | 0x80000000u;
    unsigned long long m = __ballot(u < k7);
    if (m) {
      do {
        const int l = __ffsll(m) - 1;
        m &= m - 1;
        const unsigned int uk = (unsigned int)__shfl((int)u, l);
        if (uk < k7) {
          KNN_INS_U(uk, nb + l);
        }
      } while (m);
    }
  }
  if (lane == 0) {
    skey[wave*8+0]=k0; skey[wave*8+1]=k1; skey[wave*8+2]=k2; skey[wave*8+3]=k3;
    skey[wave*8+4]=k4; skey[wave*8+5]=k5; skey[wave*8+6]=k6; skey[wave*8+7]=k7;
    sidx[wave*8+0]=id0; sidx[wave*8+1]=id1; sidx[wave*8+2]=id2; sidx[wave*8+3]=id3;
    sidx[wave*8+4]=id4; sidx[wave*8+5]=id5; sidx[wave*8+6]=id6; sidx[wave*8+7]=id7;
  }
  __syncthreads();
  if (tid == 0) {
    KNN_RESET_U();
    for (int s = 0; s < 32; ++s) {
      const unsigned int uk = skey[s];
      const int          ui = sidx[s];
      if (ulex_less(uk, ui, k7, id7)) KNN_INS_ULEX(uk, ui);
    }
    idx_out[q*8+0]=id0; idx_out[q*8+1]=id1; idx_out[q*8+2]=id2; idx_out[q*8+3]=id3;
    idx_out[q*8+4]=id4; idx_out[q*8+5]=id5; idx_out[q*8+6]=id6; idx_out[q*8+7]=id7;
  }
}

// -------------------------- inverse permutation ----------------------------
__global__ void inv_kernel(const int* __restrict__ order, int* __restrict__ inv)
{
  int i = blockIdx.x*blockDim.x + threadIdx.x;
  if (i < 4096) { int b = i >> 11, t = i & 2047; inv[(b<<11) + order[i]] = t; }
}

// -------------------------- MFMA GEMM on pre-split bf16 planes -------------
// Y = act(A[rowmap] @ Wt^T + b); A,Wt given as (hi,lo) bf16 planes [R][Kd].
// Tile 128x64, 4 waves (2x2), per-wave 4x2 frags of 16x16x32, BK=32/stage.
// M % 128 == 0, Kd % 32 == 0; Nn arbitrary (guarded).
#define GBM 128
#define GBN 64
#define GBK 32
#define GLDK 40   // padded LDS row length (bf16 units): 32 + 8
__global__ __launch_bounds__(256) void gemm_mfma(
    const unsigned short* __restrict__ Ahp, const unsigned short* __restrict__ Alp,
    const int* __restrict__ rowmap,
    const unsigned short* __restrict__ Bhp, const unsigned short* __restrict__ Blp,
    const float* __restrict__ bias,
    float* __restrict__ Y, int M, int Nn, int Kd, int act)
{
  __shared__ unsigned short Ah[GBM*GLDK], Al[GBM*GLDK];
  __shared__ unsigned short Bh[GBN*GLDK], Bl[GBN*GLDK];
  const int tid = threadIdx.x;
  const int bm = blockIdx.x, bn = blockIdx.y;
  const int wid = tid >> 6, lane = tid & 63;
  const int wr = wid >> 1, wc = wid & 1;          // 2x2 wave grid
  const int l15 = lane & 15, lk = (lane >> 4) << 3;

  // A staging: thread -> row tid>>1 (0..127), k-half (tid&1)*16 (16 shorts)
  const int sar = tid >> 1, sak = (tid & 1) << 4;
  const int agrow = bm*GBM + sar;
  const int asrc = rowmap ? rowmap[agrow] : agrow;
  const unsigned short* ArH = Ahp + (size_t)asrc * Kd + sak;
  const unsigned short* ArL = Alp + (size_t)asrc * Kd + sak;
  // B staging: thread -> row tid>>2 (0..63), k-quarter (tid&3)*8 (8 shorts)
  const int sbr = tid >> 2, sbk = (tid & 3) << 3;
  const int wrow = bn*GBN + sbr;
  const bool bok = (wrow < Nn);
  const unsigned short* BrH = Bhp + (size_t)(bok ? wrow : 0) * Kd + sbk;
  const unsigned short* BrL = Blp + (size_t)(bok ? wrow : 0) * Kd + sbk;

  f32x4 acc[4][2];
#pragma unroll
  for (int m = 0; m < 4; ++m)
#pragma unroll
    for (int n = 0; n < 2; ++n) acc[m][n] = (f32x4){0.f,0.f,0.f,0.f};

  const uint4 z4 = make_uint4(0u,0u,0u,0u);
  for (int k0 = 0; k0 < Kd; k0 += GBK) {
    // ---- stage A: 2 x uint4 per plane ----
    const int ao = sar*GLDK + sak;
    *(uint4*)&Ah[ao]     = *(const uint4*)(ArH + k0);
    *(uint4*)&Ah[ao + 8] = *(const uint4*)(ArH + k0 + 8);
    *(uint4*)&Al[ao]     = *(const uint4*)(ArL + k0);
    *(uint4*)&Al[ao + 8] = *(const uint4*)(ArL + k0 + 8);
    // ---- stage B: 1 x uint4 per plane (zero-fill OOB rows) ----
    const int bo = sbr*GLDK + sbk;
    *(uint4*)&Bh[bo] = bok ? *(const uint4*)(BrH + k0) : z4;
    *(uint4*)&Bl[bo] = bok ? *(const uint4*)(BrL + k0) : z4;
    __syncthreads();
    // ---- fragments + MFMA (one K-step of 32) ----
    bf16x8 afh[4], afl[4], bfh[2], bfl[2];
#pragma unroll
    for (int m = 0; m < 4; ++m) {
      const int row = wr*64 + m*16 + l15;
      afh[m] = *(const bf16x8*)&Ah[row*GLDK + lk];
      afl[m] = *(const bf16x8*)&Al[row*GLDK + lk];
    }
#pragma unroll
    for (int n = 0; n < 2; ++n) {
      const int row = wc*32 + n*16 + l15;
      bfh[n] = *(const bf16x8*)&Bh[row*GLDK + lk];
      bfl[n] = *(const bf16x8*)&Bl[row*GLDK + lk];
    }
#pragma unroll
    for (int m = 0; m < 4; ++m)
#pragma unroll
      for (int n = 0; n < 2; ++n) {
        acc[m][n] = __builtin_amdgcn_mfma_f32_16x16x32_bf16(afh[m], bfh[n], acc[m][n], 0,0,0);
        acc[m][n] = __builtin_amdgcn_mfma_f32_16x16x32_bf16(afh[m], bfl[n], acc[m][n], 0,0,0);
        acc[m][n] = __builtin_amdgcn_mfma_f32_16x16x32_bf16(afl[m], bfh[n], acc[m][n], 0,0,0);
      }
    __syncthreads();
  }
  // ---- epilogue: D col = lane&15, row = (lane>>4)*4 + r ----
  const int crow0 = bm*GBM + wr*64 + (lane >> 4)*4;
#pragma unroll
  for (int m = 0; m < 4; ++m) {
#pragma unroll
    for (int n = 0; n < 2; ++n) {
      const int col = bn*GBN + wc*32 + n*16 + l15;
      if (col < Nn) {
#pragma unroll
        for (int r = 0; r < 4; ++r) {
          float v = acc[m][n][r];
          if (bias) v += bias[col];
          if (act == 1) v = 0.5f*v*(1.f + erff(v*0.7071067811865475f));
          Y[(size_t)(crow0 + m*16 + r)*Nn + col] = v;
        }
      }
    }
  }
}

// -------------------------- kw softmax + neighbor mixing -------------------
__global__ __launch_bounds__(256) void kwmix_kernel(
    const float* __restrict__ QP, const float* __restrict__ wk,
    const float* __restrict__ wb, const float* __restrict__ V,
    float* __restrict__ W)
{
  const int wave = threadIdx.x >> 6, lane = threadIdx.x & 63;
  const int q = blockIdx.x*4 + wave;
  float qv[4];
#pragma unroll
  for (int j = 0; j < 4; ++j) qv[j] = QP[(size_t)q*256 + lane + 64*j];
  float logit[8];
#pragma unroll
  for (int k = 0; k < 8; ++k) {
    float p = 0.f;
#pragma unroll
    for (int j = 0; j < 4; ++j) p += qv[j]*wk[k*256 + lane + 64*j];
    for (int off = 32; off; off >>= 1) p += __shfl_xor(p, off);
    logit[k] = p + wb[k];
  }
  float mx = logit[0];
#pragma unroll
  for (int k = 1; k < 8; ++k) mx = fmaxf(mx, logit[k]);
  float e[8]; float s = 0.f;
#pragma unroll
  for (int k = 0; k < 8; ++k) { e[k] = expf(logit[k]-mx); s += e[k]; }
  float inv = 1.f/s;
  float acc[4] = {0.f,0.f,0.f,0.f};
#pragma unroll
  for (int k = 0; k < 8; ++k) {
    float kwv = e[k]*inv;
#pragma unroll
    for (int j = 0; j < 4; ++j)
      acc[j] = fmaf(kwv, V[(size_t)(q*8+k)*256 + lane + 64*j], acc[j]);
  }
#pragma unroll
  for (int j = 0; j < 4; ++j)
    W[(size_t)q*256 + lane + 64*j] = qv[j]*acc[j];
}

// -------------------------- LayerNorm over D=256 (1 wave / row) ------------
__global__ __launch_bounds__(256) void ln_kernel(
    const float* __restrict__ a, const float* __restrict__ b,
    float* __restrict__ out, int rows)
{
  const int wave = threadIdx.x >> 6, lane = threadIdx.x & 63;
  const int row = blockIdx.x*4 + wave;
  if (row >= rows) return;
  float v[4];
#pragma unroll
  for (int j = 0; j < 4; ++j) {
    float x = a[(size_t)row*256 + lane + 64*j];
    if (b) x += b[(size_t)row*256 + lane + 64*j];
    v[j] = x;
  }
  float s = v[0]+v[1]+v[2]+v[3];
  for (int off = 32; off; off >>= 1) s += __shfl_xor(s, off);
  float m = s * (1.0f/256.0f);
  float t = 0.f;
#pragma unroll
  for (int j = 0; j < 4; ++j) { float d = v[j]-m; t += d*d; }
  for (int off = 32; off; off >>= 1) t += __shfl_xor(t, off);
  float r = rsqrtf(t * (1.0f/256.0f) + 1e-5f);
#pragma unroll
  for (int j = 0; j < 4; ++j)
    out[(size_t)row*256 + lane + 64*j] = (v[j]-m)*r;
}

// unsort both paths + residual + LN (in-place on X)
__global__ __launch_bounds__(256) void ln_unsort_kernel(
    const float* __restrict__ OUTL, const int* __restrict__ INV,
    float* __restrict__ X)
{
  const int wave = threadIdx.x >> 6, lane = threadIdx.x & 63;
  const int q = blockIdx.x*4 + wave;
  const int i0 = INV[q], i1 = INV[2048 + q];
  float v[4];
#pragma unroll
  for (int j = 0; j < 4; ++j) {
    int d = lane + 64*j;
    v[j] = X[(size_t)q*256 + d]
         + 0.5f*(OUTL[(size_t)i0*256 + d] + OUTL[(size_t)(2048+i1)*256 + d]);
  }
  float s = v[0]+v[1]+v[2]+v[3];
  for (int off = 32; off; off >>= 1) s += __shfl_xor(s, off);
  float m = s * (1.0f/256.0f);
  float t = 0.f;
#pragma unroll
  for (int j = 0; j < 4; ++j) { float d = v[j]-m; t += d*d; }
  for (int off = 32; off; off >>= 1) t += __shfl_xor(t, off);
  float r = rsqrtf(t * (1.0f/256.0f) + 1e-5f);
#pragma unroll
  for (int j = 0; j < 4; ++j)
    X[(size_t)q*256 + lane + 64*j] = (v[j]-m)*r;
}

// -------------------------- causal depthwise conv (KC=4) + SiLU ------------
__global__ void conv_kernel(const float* __restrict__ PROJ,
    const float* __restrict__ Wc, const float* __restrict__ bc,
    float* __restrict__ XBC)
{
  const int c = threadIdx.x;      // 640
  const int bt = blockIdx.x;      // 4096
  const int t = bt & 2047;
  float acc = bc[c];
#pragma unroll
  for (int j = 0; j < 4; ++j) {
    int d = j - 3;
    if (t + d >= 0)
      acc = fmaf(PROJ[(size_t)(bt + d)*1160 + 512 + c], Wc[c*4+j], acc);
  }
  XBC[(size_t)bt*640 + c] = acc / (1.f + expf(-acc));  // silu
}

// -------------------------- dt softplus + dA -------------------------------
__global__ void dta_kernel(const float* __restrict__ PROJ,
    const float* __restrict__ dtb, const float* __restrict__ Alog,
    float* __restrict__ Ddt, float* __restrict__ Dda)
{
  const int i = blockIdx.x*256 + threadIdx.x;   // 32768 = 4096*8
  const int bt = i >> 3, hh = i & 7;
  float x = PROJ[(size_t)bt*1160 + 1152 + hh] + dtb[hh];
  float dt = (x > 20.f) ? x : log1pf(expf(x));
  float A = -expf(Alog[hh]);
  Ddt[hh*4096 + bt] = dt;
  Dda[hh*4096 + bt] = expf(dt * A);
}

// -------------------------- scan pass 1: per-chunk S_c, P_c ----------------
__global__ __launch_bounds__(64) void scan1_kernel(
    const float* __restrict__ XBC, const float* __restrict__ Ddt,
    const float* __restrict__ Dda, float* __restrict__ SCH, float* __restrict__ PC)
{
  const int blk = blockIdx.x;
  const int c = blk & 31, hh = (blk >> 5) & 7, b = blk >> 8;
  const int lane = threadIdx.x;
  const int t0 = (b << 11) + (c << 6);
  __shared__ float Bsh[64][64];
  __shared__ float Xsh[64][64];
  __shared__ float dAs[64], dts[64];
#pragma unroll
  for (int it = 0; it < 16; ++it) {
    int idx = it*64 + lane;
    int t = idx >> 4, c4 = (idx & 15) << 2;
    *(float4*)&Bsh[t][c4] = *(const float4*)&XBC[(size_t)(t0 + t)*640 + 512 + c4];
    *(float4*)&Xsh[t][c4] = *(const float4*)&XBC[(size_t)(t0 + t)*640 + (hh<<6) + c4];
  }
  dAs[lane] = Dda[hh*4096 + t0 + lane];
  dts[lane] = Ddt[hh*4096 + t0 + lane];
  __syncthreads();
  float h[64];
#pragma unroll
  for (int s = 0; s < 64; ++s) h[s] = 0.f;
  float p = 1.f;
  for (int t = 0; t < 64; ++t) {
    const float dA = dAs[t];
    const float u = dts[t]*Xsh[t][lane];
    p *= dA;
    const float4* B4 = (const float4*)&Bsh[t][0];
#pragma unroll
    for (int s4 = 0; s4 < 16; ++s4) {
      float4 bv = B4[s4];
      h[4*s4+0] = fmaf(h[4*s4+0], dA, bv.x*u);
      h[4*s4+1] = fmaf(h[4*s4+1], dA, bv.y*u);
      h[4*s4+2] = fmaf(h[4*s4+2], dA, bv.z*u);
      h[4*s4+3] = fmaf(h[4*s4+3], dA, bv.w*u);
    }
  }
  float* op = SCH + (size_t)blk*4096 + lane*64;
#pragma unroll
  for (int s4 = 0; s4 < 16; ++s4)
    ((float4*)op)[s4] = make_float4(h[4*s4], h[4*s4+1], h[4*s4+2], h[4*s4+3]);
  if (lane == 0) PC[blk] = p;
}

// -------------------------- sequential cross-chunk combine (in-place) ------
__global__ void combine_kernel(float* __restrict__ SCH, const float* __restrict__ PC)
{
  const int tid = blockIdx.x*256 + threadIdx.x;   // 65536
  const int bh = tid >> 12, ds = tid & 4095;
  float h = 0.f;
  for (int cc = 0; cc < 32; ++cc) {
    size_t o = ((size_t)(bh*32 + cc) << 12) + ds;
    float s = SCH[o];
    SCH[o] = h;
    h = fmaf(h, PC[bh*32+cc], s);
  }
}

// -------------------------- scan pass 2: exact recurrence + y --------------
__global__ __launch_bounds__(64) void scan2_kernel(
    const float* __restrict__ XBC, const float* __restrict__ Ddt,
    const float* __restrict__ Dda, const float* __restrict__ HST,
    const float* __restrict__ Dm, float* __restrict__ Yout)
{
  const int blk = blockIdx.x;
  const int c = blk & 31, hh = (blk >> 5) & 7, b = blk >> 8;
  const int lane = threadIdx.x;
  const int t0 = (b << 11) + (c << 6);
  __shared__ float Bsh[64][64];
  __shared__ float Csh[64][64];
  __shared__ float Xsh[64][64];
  __shared__ float dAs[64], dts[64];
#pragma unroll
  for (int it = 0; it < 16; ++it) {
    int idx = it*64 + lane;
    int t = idx >> 4, c4 = (idx & 15) << 2;
    *(float4*)&Bsh[t][c4] = *(const float4*)&XBC[(size_t)(t0 + t)*640 + 512 + c4];
    *(float4*)&Csh[t][c4] = *(const float4*)&XBC[(size_t)(t0 + t)*640 + 576 + c4];
    *(float4*)&Xsh[t][c4] = *(const float4*)&XBC[(size_t)(t0 + t)*640 + (hh<<6) + c4];
  }
  dAs[lane] = Dda[hh*4096 + t0 + lane];
  dts[lane] = Ddt[hh*4096 + t0 + lane];
  const float Dh = Dm[hh];
  float h[64];
  const float4* hp = (const float4*)(HST + (size_t)blk*4096 + lane*64);
#pragma unroll
  for (int s4 = 0; s4 < 16; ++s4) {
    float4 t4 = hp[s4];
    h[4*s4+0]=t4.x; h[4*s4+1]=t4.y; h[4*s4+2]=t4.z; h[4*s4+3]=t4.w;
  }
  __syncthreads();
  for (int t = 0; t < 64; ++t) {
    const float dA = dAs[t];
    const float u = dts[t]*Xsh[t][lane];
    float y = 0.f;
    const float4* B4 = (const float4*)&Bsh[t][0];
    const float4* C4 = (const float4*)&Csh[t][0];
#pragma unroll
    for (int s4 = 0; s4 < 16; ++s4) {
      float4 bv = B4[s4];
      float4 cv = C4[s4];
      h[4*s4+0] = fmaf(h[4*s4+0], dA, bv.x*u); y = fmaf(cv.x, h[4*s4+0], y);
      h[4*s4+1] = fmaf(h[4*s4+1], dA, bv.y*u); y = fmaf(cv.y, h[4*s4+1], y);
      h[4*s4+2] = fmaf(h[4*s4+2], dA, bv.z*u); y = fmaf(cv.z, h[4*s4+2], y);
      h[4*s4+3] = fmaf(h[4*s4+3], dA, bv.w*u); y = fmaf(cv.w, h[4*s4+3], y);
    }
    Yout[(size_t)(t0 + t)*512 + (hh<<6) + lane] = y + Dh*Xsh[t][lane];
  }
}

// -------------------------- gate (silu(z)) + RMSNorm over 512 (in-place) ---
__global__ __launch_bounds__(256) void gaterms_kernel(
    float* __restrict__ Y, const float* __restrict__ PROJ,
    const float* __restrict__ rmsw)
{
  const int wave = threadIdx.x >> 6, lane = threadIdx.x & 63;
  const int row = blockIdx.x*4 + wave;   // 4096
  float v[8]; float ss = 0.f;
#pragma unroll
  for (int j = 0; j < 8; ++j) {
    float y = Y[(size_t)row*512 + lane + 64*j];
    float z = PROJ[(size_t)row*1160 + lane + 64*j];
    float g = y * (z / (1.f + expf(-z)));
    v[j] = g; ss += g*g;
  }
  for (int off = 32; off; off >>= 1) ss += __shfl_xor(ss, off);
  float r = rsqrtf(ss * (1.0f/512.0f) + 1e-5f);
#pragma unroll
  for (int j = 0; j < 8; ++j)
    Y[(size_t)row*512 + lane + 64*j] = v[j] * r * rmsw[lane + 64*j];
}

// ---------------------------------------------------------------------------
extern "C" void kernel_launch(void* const* d_in, const int* in_sizes, int n_in,
                              void* d_out, int out_size, void* d_ws, size_t ws_size,
                              hipStream_t stream)
{
  (void)in_sizes; (void)n_in; (void)out_size; (void)ws_size;
  const float* query = (const float*)d_in[0];
  const float* qpos  = (const float*)d_in[1];
  const float* feats = (const float*)d_in[2];
  const float* spos  = (const float*)d_in[3];
  const float* w_q   = (const float*)d_in[4];
  const float* w_v   = (const float*)d_in[5];
  const float* w_o   = (const float*)d_in[6];
  const float* w_k   = (const float*)d_in[7];
  const float* w_b   = (const float*)d_in[8];
  const float* Win   = (const float*)d_in[9];
  const float* Wconv = (const float*)d_in[10];
  const float* bconv = (const float*)d_in[11];
  const float* Alog  = (const float*)d_in[12];
  const float* Dm    = (const float*)d_in[13];
  const float* dtb   = (const float*)d_in[14];
  const float* rmsw  = (const float*)d_in[15];
  const float* Wout  = (const float*)d_in[16];
  const float* fw1   = (const float*)d_in[17];
  const float* fb1   = (const float*)d_in[18];
  const float* fw2   = (const float*)d_in[19];
  const float* fb2   = (const float*)d_in[20];
  const int*   order = (const int*)d_in[21];
  float* out = (float*)d_out;

  char* ws = (char*)d_ws;
  size_t off = 0;
  auto alloc = [&](size_t bytes) -> void* {
    void* p = ws + off;
    off = (off + bytes + 255) & ~(size_t)255;
    return p;
  };
  int*   IDX = (int*)alloc((size_t)2048*8*4);
  int*   INV = (int*)alloc((size_t)4096*4);
  float* PC  = (float*)alloc((size_t)512*4);
  float4* P4 = (float4*)alloc((size_t)32768*16);
  float* Ddt = (float*)alloc((size_t)4096*8*4);
  float* Dda = (float*)alloc((size_t)4096*8*4);
  float* QP  = (float*)alloc((size_t)2048*256*4);
  float* WB  = (float*)alloc((size_t)2048*256*4);
  float* WO  = (float*)alloc((size_t)2048*256*4);
  float* X   = (float*)alloc((size_t)2048*256*4);
  float* XN  = (float*)alloc((size_t)2048*256*4);
  float* U1  = (float*)alloc((size_t)4096*1160*4);  // V (16MB) | PROJ (19MB)
  float* U2  = (float*)alloc((size_t)4096*640*4);   // XBC (10.5MB) | FFH (8.4MB)
  float* SCH = (float*)alloc((size_t)512*4096*4);   // chunk states
  float* Yb  = (float*)alloc((size_t)4096*512*4);
  float* U6  = (float*)alloc((size_t)4096*256*4);   // OUTL | FFO
  // bf16 split planes
  unsigned short* Qh  = (unsigned short*)alloc((size_t)2048*256*2);
  unsigned short* Ql  = (unsigned short*)alloc((size_t)2048*256*2);
  unsigned short* U7h = (unsigned short*)alloc((size_t)32768*256*2); // feats | FFH planes
  unsigned short* U7l = (unsigned short*)alloc((size_t)32768*256*2);
  unsigned short* WBh = (unsigned short*)alloc((size_t)2048*256*2);
  unsigned short* WBl = (unsigned short*)alloc((size_t)2048*256*2);
  unsigned short* XNh = (unsigned short*)alloc((size_t)2048*256*2);
  unsigned short* XNl = (unsigned short*)alloc((size_t)2048*256*2);
  unsigned short* Ybh = (unsigned short*)alloc((size_t)4096*512*2);
  unsigned short* Ybl = (unsigned short*)alloc((size_t)4096*512*2);
  unsigned short* Xh  = (unsigned short*)alloc((size_t)2048*256*2);
  unsigned short* Xl  = (unsigned short*)alloc((size_t)2048*256*2);
  unsigned short* Wqh = (unsigned short*)alloc((size_t)256*256*2);
  unsigned short* Wql = (unsigned short*)alloc((size_t)256*256*2);
  unsigned short* Wvh = (unsigned short*)alloc((size_t)256*256*2);
  unsigned short* Wvl = (unsigned short*)alloc((size_t)256*256*2);
  unsigned short* Woh = (unsigned short*)alloc((size_t)256*256*2);
  unsigned short* Wol = (unsigned short*)alloc((size_t)256*256*2);
  unsigned short* Wih = (unsigned short*)alloc((size_t)2*1160*256*2);
  unsigned short* Wil = (unsigned short*)alloc((size_t)2*1160*256*2);
  unsigned short* Wuh = (unsigned short*)alloc((size_t)2*256*512*2);
  unsigned short* Wul = (unsigned short*)alloc((size_t)2*256*512*2);
  unsigned short* F1h = (unsigned short*)alloc((size_t)1024*256*2);
  unsigned short* F1l = (unsigned short*)alloc((size_t)1024*256*2);
  unsigned short* F2h = (unsigned short*)alloc((size_t)256*1024*2);
  unsigned short* F2l = (unsigned short*)alloc((size_t)256*1024*2);
  float* Vb   = U1;  float* PROJ = U1;
  float* XBC  = U2;  float* FFH  = U2;
  float* OUTL = U6;  float* FFO  = U6;
  unsigned short* FFHh = U7h;  // feats planes dead after stage 1
  unsigned short* FFHl = U7l;

  auto cvt = [&](const float* s, unsigned short* h, unsigned short* l, int n) {
    cvt_kernel<<<(n/4 + 255)/256, 256, 0, stream>>>(s, h, l, n/4);
  };

  // --- stage 1: KNN + aggregation ---
  inv_kernel<<<16, 256, 0, stream>>>(order, INV);
  prep_kernel<<<128, 256, 0, stream>>>(spos, P4);
  knn_kernel<<<2048, 256, 0, stream>>>(qpos, P4, IDX);
  // weight + input conversions (one-time)
  cvt(query, Qh, Ql, 2048*256);
  cvt(feats, U7h, U7l, 32768*256);
  cvt(w_q, Wqh, Wql, 256*256);
  cvt(w_v, Wvh, Wvl, 256*256);
  cvt(w_o, Woh, Wol, 256*256);
  cvt(Win, Wih, Wil, 2*1160*256);
  cvt(Wout, Wuh, Wul, 2*256*512);
  cvt(fw1, F1h, F1l, 1024*256);
  cvt(fw2, F2h, F2l, 256*1024);
  gemm_mfma<<<dim3(16,4), 256, 0, stream>>>(Qh, Ql, nullptr, Wqh, Wql, nullptr,
                                            QP, 2048,256,256,0);
  gemm_mfma<<<dim3(128,4), 256, 0, stream>>>(U7h, U7l, IDX, Wvh, Wvl, nullptr,
                                             Vb, 16384,256,256,0);
  kwmix_kernel<<<512, 256, 0, stream>>>(QP, w_k, w_b, Vb, WB);
  cvt(WB, WBh, WBl, 2048*256);
  gemm_mfma<<<dim3(16,4), 256, 0, stream>>>(WBh, WBl, nullptr, Woh, Wol, nullptr,
                                            WO, 2048,256,256,0);
  ln_kernel<<<512, 256, 0, stream>>>(WO, query, X, 2048);

  // --- stage 2: two Mamba2 layers ---
  for (int l = 0; l < 2; ++l) {
    ln_kernel<<<512, 256, 0, stream>>>(X, nullptr, XN, 2048);
    cvt(XN, XNh, XNl, 2048*256);
    gemm_mfma<<<dim3(32,19), 256, 0, stream>>>(XNh, XNl, order,
                                               Wih + (size_t)l*1160*256,
                                               Wil + (size_t)l*1160*256,
                                               nullptr, PROJ, 4096,1160,256,0);
    conv_kernel<<<4096, 640, 0, stream>>>(PROJ, Wconv + l*640*4, bconv + l*640, XBC);
    dta_kernel<<<128, 256, 0, stream>>>(PROJ, dtb + l*8, Alog + l*8, Ddt, Dda);
    scan1_kernel<<<512, 64, 0, stream>>>(XBC, Ddt, Dda, SCH, PC);
    combine_kernel<<<256, 256, 0, stream>>>(SCH, PC);
    scan2_kernel<<<512, 64, 0, stream>>>(XBC, Ddt, Dda, SCH, Dm + l*8, Yb);
    gaterms_kernel<<<1024, 256, 0, stream>>>(Yb, PROJ, rmsw + l*512);
    cvt(Yb, Ybh, Ybl, 4096*512);
    gemm_mfma<<<dim3(32,4), 256, 0, stream>>>(Ybh, Ybl, nullptr,
                                              Wuh + (size_t)l*256*512,
                                              Wul + (size_t)l*256*512,
                                              nullptr, OUTL, 4096,256,512,0);
    ln_unsort_kernel<<<512, 256, 0, stream>>>(OUTL, INV, X);
  }

  // --- stage 3: FFN ---
  cvt(X, Xh, Xl, 2048*256);
  gemm_mfma<<<dim3(16,16), 256, 0, stream>>>(Xh, Xl, nullptr, F1h, F1l, fb1,
                                             FFH, 2048,1024,256,1);
  cvt(FFH, FFHh, FFHl, 2048*1024);
  gemm_mfma<<<dim3(16,4), 256, 0, stream>>>(FFHh, FFHl, nullptr, F2h, F2l, fb2,
                                            FFO, 2048,256,1024,0);
  ln_kernel<<<512, 256, 0, stream>>>(FFO, X, out, 2048);
}